// Round 10
// baseline (113.654 us; speedup 1.0000x reference)
//
#include <hip/hip_runtime.h>

typedef unsigned int uint_t;
typedef unsigned long long u64_t;

constexpr int B = 8;
constexpr int N = 1024;
constexpr int NBLOCKS = 256;
constexpr int NTHREADS = 512;
constexpr int NWAVES = NTHREADS / 64;      // 8
constexpr int BPB = NBLOCKS / B;           // 32 blocks per batch
constexpr int SEG = N / BPB;               // 32 rows per block
constexpr int RPW = SEG / NWAVES;          // 4 rows per wave
constexpr int KPL = N / 64;                // 16 columns per lane
constexpr int MAX_ITER = 100;
constexpr float THRESH = 0.1f;
constexpr float K2 = 14.42695040888963f;         // log2(e)/EPS
constexpr float A2K = 2.0f * K2;
constexpr float NEPSLN2 = -0.06931471805599453f; // -EPS*ln2
constexpr float EPSLOGMU = -0.693146156565634f;  // EPS*log(1/N+1e-8)

// ws offsets in u64 units. u/v are TAGGED cells (epoch<<32)|float_bits,
// double-buffered by iteration parity. Exact-tag polling means NO zero-init
// is needed anywhere: 0xAA poison can never equal a tag (tags <= 102).
constexpr int Q_U    = 0;                       // [2][B][N]
constexpr int Q_V    = Q_U + 2 * B * N;         // [2][B][N]
constexpr int Q_ERRA = Q_V + 2 * B * N;         // [B][2][256] ring-2 per-wave errs
constexpr int Q_ERRB = Q_ERRA + B * 2 * 256;    // [4][B] ring-4 batch errs
constexpr int Q_EMD  = Q_ERRB + 4 * B;          // [NBLOCKS] tagged emd partials

__device__ __forceinline__ u64_t l64(const u64_t* p) {
  return __hip_atomic_load(p, __ATOMIC_RELAXED, __HIP_MEMORY_SCOPE_AGENT);
}
__device__ __forceinline__ void s64(u64_t* p, u64_t v) {
  __hip_atomic_store(p, v, __ATOMIC_RELAXED, __HIP_MEMORY_SCOPE_AGENT);
}
__device__ __forceinline__ u64_t pk64(uint_t tag, float v) {
  return ((u64_t)tag << 32) | (u64_t)__float_as_uint(v);
}
__device__ __forceinline__ uint_t tg(u64_t v) { return (uint_t)(v >> 32); }
__device__ __forceinline__ float pay(u64_t v) { return __uint_as_float((uint_t)v); }

__device__ __forceinline__ float wsum(float v) {
#pragma unroll
  for (int o = 32; o; o >>= 1) v += __shfl_xor(v, o);
  return v;
}
__device__ __forceinline__ float wmax(float v) {
#pragma unroll
  for (int o = 32; o; o >>= 1) v = fmaxf(v, __shfl_xor(v, o));
  return v;
}

// Deterministic block-wide sum (epilogue only).
__device__ __forceinline__ float block_sum(float v, float* sh) {
  v = wsum(v);
  const int wave = threadIdx.x >> 6;
  const int lane = threadIdx.x & 63;
  if (lane == 0) sh[wave] = v;
  __syncthreads();
  float tot = 0.f;
#pragma unroll
  for (int w = 0; w < NWAVES; ++w) tot += sh[w];
  __syncthreads();
  return tot;
}

// Poll this lane's 16 tagged cells until all match `want` exactly; the poll
// IS the synchronization (value and readiness travel in one 8B word).
__device__ __forceinline__ void poll16(const u64_t* base, uint_t want, int lane,
                                       float (&out)[KPL]) {
  u64_t pk[KPL];
#pragma unroll
  for (int k = 0; k < KPL; ++k) pk[k] = l64(&base[lane + (k << 6)]);
  for (;;) {
    bool ok = true;
#pragma unroll
    for (int k = 0; k < KPL; ++k) ok &= (tg(pk[k]) == want);
    if (__all(ok)) break;
    __builtin_amdgcn_s_sleep(1);
#pragma unroll
    for (int k = 0; k < KPL; ++k)
      if (tg(pk[k]) != want) pk[k] = l64(&base[lane + (k << 6)]);
  }
#pragma unroll
  for (int k = 0; k < KPL; ++k) out[k] = pay(pk[k]) * K2;
}

// One Sinkhorn half-update in base-2 scale (K2 folded in). Input potential
// polled from tagged cells (tag_in); output rows stored tagged (tag_out).
// Cols from float2-pair LDS (conflict-free); rows wave-uniform broadcasts.
// err meaningful on lane 0 only.
template <bool TRACK, bool PIN_ZERO>
__device__ __forceinline__ float half_compute(
    const float2* __restrict__ cxy, const float2* __restrict__ czw,
    const float2* __restrict__ rxy, const float2* __restrict__ rzw,
    const u64_t* __restrict__ pin, u64_t* __restrict__ pout,
    uint_t tag_in, uint_t tag_out,
    const float (&prev)[RPW], float (&pnew)[RPW], int i0, int lane) {
  float p2[KPL];
  if (PIN_ZERO) {
#pragma unroll
    for (int k = 0; k < KPL; ++k) p2[k] = 0.f;
  } else {
    poll16(pin, tag_in, lane, p2);
  }

  float a0[RPW], a1[RPW], a2[RPW], X[RPW], m[RPW];
  float vals[RPW][KPL];
#pragma unroll
  for (int rr = 0; rr < RPW; ++rr) {
    float2 rA = rxy[i0 + rr], rB = rzw[i0 + rr];   // broadcast
    a0[rr] = A2K * rA.x; a1[rr] = A2K * rA.y; a2[rr] = A2K * rB.x;
    X[rr] = -rB.y;                       // rB.y = -K2*|r|^2
    m[rr] = -3.4e38f;
  }
#pragma unroll
  for (int k = 0; k < KPL; ++k) {
    const int j = lane + (k << 6);
    float2 cA = cxy[j], cB = czw[j];
    float base = cB.y + p2[k];           // fold pin into the fma chain
#pragma unroll
    for (int rr = 0; rr < RPW; ++rr) {
      float t = fmaf(a0[rr], cA.x, fmaf(a1[rr], cA.y, fmaf(a2[rr], cB.x, base)));
      float val = fminf(t - X[rr], p2[k]);  // = p2 - K2*max(C,0)
      vals[rr][k] = val;
      m[rr] = fmaxf(m[rr], val);
    }
  }
  float err = 0.f;
#pragma unroll
  for (int rr = 0; rr < RPW; ++rr) {
    float mr = wmax(m[rr]);
    float s = 0.f;
#pragma unroll
    for (int k = 0; k < KPL; ++k)
      s += __builtin_amdgcn_exp2f(vals[rr][k] - mr);
    s = wsum(s);
    float pn = fmaf(NEPSLN2, mr + __builtin_amdgcn_logf(s), EPSLOGMU);
    pnew[rr] = pn;
    if (lane == 0) {
      s64(&pout[i0 + rr], pk64(tag_out, pn));   // tagged store: value IS flag
      if (TRACK) err += fabsf(pn - prev[rr]);
    }
  }
  return err;
}

__global__ void __launch_bounds__(NTHREADS, 2) sinkhorn_kernel(
    const float* __restrict__ xg, const float* __restrict__ yg,
    float* __restrict__ out, float* __restrict__ wsf) {
  __shared__ float2 s_xxy[N], s_xzw[N];   // (x,y) and (z, -K2*|p|^2)
  __shared__ float2 s_yxy[N], s_yzw[N];
  __shared__ float sh_red[NWAVES];

  u64_t* ws = (u64_t*)wsf;
  const int bid = blockIdx.x;
  const int tid = threadIdx.x;
  const int b = bid & 7;
  const int seg = bid >> 3;
  const int wave = tid >> 6;
  const int lane = tid & 63;
  const int i0 = seg * SEG + wave * RPW;   // first of this wave's rows

  u64_t* u0 = ws + Q_U + (size_t)b * N;            // parity 0
  u64_t* u1 = ws + Q_U + (size_t)(B + b) * N;      // parity 1
  u64_t* v0 = ws + Q_V + (size_t)b * N;
  u64_t* v1 = ws + Q_V + (size_t)(B + b) * N;
  u64_t* errA = ws + Q_ERRA + (size_t)b * 512;     // [2][256] ring-2
  u64_t* errB = ws + Q_ERRB;                       // [4][B] ring-4
  u64_t* emdF = ws + Q_EMD;                        // [NBLOCKS]

  // Stage points into LDS: fully-coalesced (3 float2 per thread = 2 points).
  {
    const float2* xp = (const float2*)(xg + (size_t)b * N * 3) + 3 * tid;
    float2 g0 = xp[0], g1 = xp[1], g2 = xp[2];
    s_xxy[2 * tid]     = g0;
    s_xzw[2 * tid]     = make_float2(g1.x, -K2 * (g0.x * g0.x + g0.y * g0.y + g1.x * g1.x));
    s_xxy[2 * tid + 1] = make_float2(g1.y, g2.x);
    s_xzw[2 * tid + 1] = make_float2(g2.y, -K2 * (g1.y * g1.y + g2.x * g2.x + g2.y * g2.y));
    const float2* yp = (const float2*)(yg + (size_t)b * N * 3) + 3 * tid;
    float2 h0 = yp[0], h1 = yp[1], h2 = yp[2];
    s_yxy[2 * tid]     = h0;
    s_yzw[2 * tid]     = make_float2(h1.x, -K2 * (h0.x * h0.x + h0.y * h0.y + h1.x * h1.x));
    s_yxy[2 * tid + 1] = make_float2(h1.y, h2.x);
    s_yzw[2 * tid + 1] = make_float2(h2.y, -K2 * (h1.y * h1.y + h2.x * h2.x + h2.y * h2.y));
  }
  __syncthreads();

  // ---- u-half(0): u_1 from v_0 = 0; store tagged (tag 1, parity 1) ----
  float un[RPW], un_prev[RPW];
#pragma unroll
  for (int rr = 0; rr < RPW; ++rr) un_prev[rr] = 0.f;
  float my_err = half_compute<true, true>(s_yxy, s_yzw, s_xxy, s_xzw,
                                          nullptr, u1, 0u, 1u,
                                          un_prev, un, i0, lane);
  {
    float we = wsum(my_err);
    if (lane == 0) s64(&errA[0 * 256 + seg * 8 + wave], pk64(1u, we));
  }

  int it = 0;
  int final_it;
  bool use_prev;
  for (;;) {
    const uint_t want = (uint_t)(it + 1);
    u64_t* ucur = ((it + 1) & 1) ? u1 : u0;   // holds u_{it+1}
    u64_t* vcur = ((it + 1) & 1) ? v1 : v0;   // will hold v_{it+1}

    // ---- v-half(it): poll u_{it+1} (the poll IS the sync), store v_{it+1} ----
    float vn[RPW], vdummy[RPW];
    half_compute<false, false>(s_xxy, s_xzw, s_yxy, s_yzw,
                               ucur, vcur, want, want, vdummy, vn, i0, lane);

    // ---- seg0-wave0 aggregates batch err(it): partials are one compute
    // phase old -> poll hits immediately. Publishes tagged errB. ----
    if (seg == 0 && wave == 0) {
      const u64_t* ea = errA + (it & 1) * 256;
      u64_t pa[4];
#pragma unroll
      for (int q = 0; q < 4; ++q) pa[q] = l64(&ea[lane + (q << 6)]);
      for (;;) {
        bool ok = true;
#pragma unroll
        for (int q = 0; q < 4; ++q) ok &= (tg(pa[q]) == want);
        if (__all(ok)) break;
        __builtin_amdgcn_s_sleep(1);
#pragma unroll
        for (int q = 0; q < 4; ++q)
          if (tg(pa[q]) != want) pa[q] = l64(&ea[lane + (q << 6)]);
      }
      float e = 0.f;
#pragma unroll
      for (int q = 0; q < 4; ++q) e += pay(pa[q]);
      e = wsum(e);
      if (lane == 0) s64(&errB[(it & 3) * 8 + b], pk64(want, e));
    }

    if (it == MAX_ITER - 1) { final_it = MAX_ITER; use_prev = false; break; }

    // Prefetch decision(it) inputs (checked after the next u-half).
    u64_t dp = (lane < B) ? l64(&errB[(it & 3) * 8 + lane]) : 0;

    // ---- u-half(it+1): poll v_{it+1}, store u_{it+2} (tag it+2) ----
#pragma unroll
    for (int rr = 0; rr < RPW; ++rr) un_prev[rr] = un[rr];
    u64_t* unxt = ((it + 2) & 1) ? u1 : u0;
    my_err = half_compute<true, false>(s_yxy, s_yzw, s_xxy, s_xzw,
                                       vcur, unxt, want, (uint_t)(it + 2),
                                       un_prev, un, i0, lane);
    {
      float we = wsum(my_err);
      if (lane == 0)
        s64(&errA[((it + 1) & 1) * 256 + seg * 8 + wave], pk64((uint_t)(it + 2), we));
    }

    // ---- lagged decision(it): prefetched, per-wave, uniform verdict ----
    for (;;) {
      bool ok = (lane >= B) || (tg(dp) == want);
      if (__all(ok)) break;
      __builtin_amdgcn_s_sleep(1);
      if (lane < B && tg(dp) != want) dp = l64(&errB[(it & 3) * 8 + lane]);
    }
    float tot = wsum((lane < B) ? pay(dp) : 0.f);
    if (tot * (1.f / (B * N)) < THRESH) {
      final_it = it + 1; use_prev = true;   // keep u_{it+1} (=un_prev), v_{it+1}
      break;
    }
    ++it;
  }

  // ---- epilogue: emd_b = sum_ij exp((u_i+v_j-C)/EPS)*C  (in K2 scale) ----
  u64_t* vfin = (final_it & 1) ? v1 : v0;
  float p2e[KPL];
  poll16(vfin, (uint_t)final_it, lane, p2e);  // mostly pre-satisfied
  float acc = 0.f;
#pragma unroll
  for (int rr = 0; rr < RPW; ++rr) {
    const int i = i0 + rr;
    float2 rA = s_xxy[i], rB = s_xzw[i];
    float a0 = A2K * rA.x, a1 = A2K * rA.y, a2 = A2K * rB.x;
    float X = -rB.y;
    float u2 = (use_prev ? un_prev[rr] : un[rr]) * K2;
#pragma unroll
    for (int k = 0; k < KPL; ++k) {
      const int j = lane + (k << 6);
      float2 cA = s_yxy[j], cB = s_yzw[j];
      float t = fmaf(a0, cA.x, fmaf(a1, cA.y, fmaf(a2, cB.x, cB.y)));
      float kc = fmaxf(X - t, 0.f);   // K2*C
      acc = fmaf(__builtin_amdgcn_exp2f(u2 + p2e[k] - kc), kc, acc);
    }
  }
  float blk = block_sum(acc, sh_red);
  const uint_t ef = (uint_t)(final_it + 1);   // grid-uniform
  if (tid == 0) s64(&emdF[bid], pk64(ef, blk));

  // Block 0 polls all 256 tagged partials directly (one hop).
  if (bid == 0) {
    float part = 0.f;
    if (wave < 4) {
      u64_t pk = l64(&emdF[(wave << 6) + lane]);
      for (;;) {
        if (__all(tg(pk) == ef)) break;
        __builtin_amdgcn_s_sleep(1);
        if (tg(pk) != ef) pk = l64(&emdF[(wave << 6) + lane]);
      }
      part = pay(pk);
    }
    float tot = block_sum(part, sh_red);
    if (tid == 0) out[0] = tot * (1.f / (B * K2));
  }
}

extern "C" void kernel_launch(void* const* d_in, const int* in_sizes, int n_in,
                              void* d_out, int out_size, void* d_ws, size_t ws_size,
                              hipStream_t stream) {
  const float* x = (const float*)d_in[0];
  const float* y = (const float*)d_in[1];
  float* out = (float*)d_out;
  float* ws = (float*)d_ws;
  void* args[] = { (void*)&x, (void*)&y, (void*)&out, (void*)&ws };
  // Cooperative launch only for the co-residency guarantee. All sync is
  // tagged-value polling (exact epoch match) over coherent atomics — no
  // barriers, no flags, no init pass.
  hipLaunchCooperativeKernel((const void*)sinkhorn_kernel,
                             dim3(NBLOCKS), dim3(NTHREADS), args, 0, stream);
}

// Round 11
// 109.646 us; speedup vs baseline: 1.0366x; 1.0366x over previous
//
#include <hip/hip_runtime.h>

typedef unsigned int uint_t;
typedef unsigned long long u64_t;

constexpr int B = 8;
constexpr int N = 1024;
constexpr int NBLOCKS = 256;
constexpr int NTHREADS = 512;
constexpr int NWAVES = NTHREADS / 64;      // 8
constexpr int BPB = NBLOCKS / B;           // 32 blocks per batch
constexpr int SEG = N / BPB;               // 32 rows per block
constexpr int RPW = SEG / NWAVES;          // 4 rows per wave
constexpr int KPL = N / 64;                // 16 columns per lane
constexpr int MAX_ITER = 100;
constexpr float THRESH = 0.1f;
constexpr float K2 = 14.42695040888963f;         // log2(e)/EPS
constexpr float A2K = 2.0f * K2;
constexpr float NEPSLN2 = -0.06931471805599453f; // -EPS*ln2
constexpr float EPSLOGMU = -0.693146156565634f;  // EPS*log(1/N+1e-8)

// ws offsets in u64 units. u/v are TAGGED cells (epoch<<32)|float_bits,
// double-buffered by parity. Exact-tag polling -> no zero-init anywhere
// (0xAA poison never equals a tag <= 102).
constexpr int Q_U    = 0;                       // [2][B][N]
constexpr int Q_V    = Q_U + 2 * B * N;         // [2][B][N]
constexpr int Q_ERRA = Q_V + 2 * B * N;         // [B][2][256] ring-2 per-wave errs
constexpr int Q_ERRB = Q_ERRA + B * 2 * 256;    // [4][B] ring-4 batch errs
constexpr int Q_EMD  = Q_ERRB + 4 * B;          // [NBLOCKS] tagged emd partials

__device__ __forceinline__ u64_t l64(const u64_t* p) {
  return __hip_atomic_load(p, __ATOMIC_RELAXED, __HIP_MEMORY_SCOPE_AGENT);
}
__device__ __forceinline__ void s64(u64_t* p, u64_t v) {
  __hip_atomic_store(p, v, __ATOMIC_RELAXED, __HIP_MEMORY_SCOPE_AGENT);
}
__device__ __forceinline__ u64_t pk64(uint_t tag, float v) {
  return ((u64_t)tag << 32) | (u64_t)__float_as_uint(v);
}
__device__ __forceinline__ uint_t tg(u64_t v) { return (uint_t)(v >> 32); }
__device__ __forceinline__ float pay(u64_t v) { return __uint_as_float((uint_t)v); }

__device__ __forceinline__ float wsum(float v) {
#pragma unroll
  for (int o = 32; o; o >>= 1) v += __shfl_xor(v, o);
  return v;
}
__device__ __forceinline__ float wmax(float v) {
#pragma unroll
  for (int o = 32; o; o >>= 1) v = fmaxf(v, __shfl_xor(v, o));
  return v;
}

// Deterministic block-wide sum (epilogue only).
__device__ __forceinline__ float block_sum(float v, float* sh) {
  v = wsum(v);
  const int wave = threadIdx.x >> 6;
  const int lane = threadIdx.x & 63;
  if (lane == 0) sh[wave] = v;
  __syncthreads();
  float tot = 0.f;
#pragma unroll
  for (int w = 0; w < NWAVES; ++w) tot += sh[w];
  __syncthreads();
  return tot;
}

// Poll this lane's 16 tagged cells until all match `want` exactly.
__device__ __forceinline__ void poll16(const u64_t* base, uint_t want, int lane,
                                       float (&out)[KPL]) {
  u64_t pk[KPL];
#pragma unroll
  for (int k = 0; k < KPL; ++k) pk[k] = l64(&base[lane + (k << 6)]);
  for (;;) {
    bool ok = true;
#pragma unroll
    for (int k = 0; k < KPL; ++k) ok &= (tg(pk[k]) == want);
    if (__all(ok)) break;
    __builtin_amdgcn_s_sleep(1);
#pragma unroll
    for (int k = 0; k < KPL; ++k)
      if (tg(pk[k]) != want) pk[k] = l64(&base[lane + (k << 6)]);
  }
#pragma unroll
  for (int k = 0; k < KPL; ++k) out[k] = pay(pk[k]) * K2;
}

// One Sinkhorn half-update in base-2 scale (K2 folded in). KEY CHANGE (R11):
// only WAVE 0 polls the tagged input cells (8 KB/round per BLOCK, not per
// wave — R10 had all 8 waves redundantly polling identical data, ~2.3 TB/s
// of coherence-point read traffic that queued ahead of producer stores);
// payloads are broadcast via an LDS buffer (stride-1, conflict-free),
// double-buffered by call parity (s_p2 arg). One __syncthreads per half.
template <bool TRACK, bool PIN_ZERO>
__device__ __forceinline__ float half_compute(
    const float2* __restrict__ cxy, const float2* __restrict__ czw,
    const float2* __restrict__ rxy, const float2* __restrict__ rzw,
    const u64_t* __restrict__ pin, u64_t* __restrict__ pout,
    uint_t tag_in, uint_t tag_out, float* __restrict__ s_p2,
    const float (&prev)[RPW], float (&pnew)[RPW], int i0, int wave, int lane) {
  float p2[KPL];
  if (PIN_ZERO) {
#pragma unroll
    for (int k = 0; k < KPL; ++k) p2[k] = 0.f;
  } else {
    if (wave == 0) {
      poll16(pin, tag_in, lane, p2);
#pragma unroll
      for (int k = 0; k < KPL; ++k) s_p2[lane + (k << 6)] = p2[k];
    }
    __syncthreads();
    if (wave != 0) {
#pragma unroll
      for (int k = 0; k < KPL; ++k) p2[k] = s_p2[lane + (k << 6)];
    }
  }

  float a0[RPW], a1[RPW], a2[RPW], X[RPW], m[RPW];
  float vals[RPW][KPL];
#pragma unroll
  for (int rr = 0; rr < RPW; ++rr) {
    float2 rA = rxy[i0 + rr], rB = rzw[i0 + rr];   // broadcast
    a0[rr] = A2K * rA.x; a1[rr] = A2K * rA.y; a2[rr] = A2K * rB.x;
    X[rr] = -rB.y;                       // rB.y = -K2*|r|^2
    m[rr] = -3.4e38f;
  }
#pragma unroll
  for (int k = 0; k < KPL; ++k) {
    const int j = lane + (k << 6);
    float2 cA = cxy[j], cB = czw[j];
    float base = cB.y + p2[k];           // fold pin into the fma chain
#pragma unroll
    for (int rr = 0; rr < RPW; ++rr) {
      float t = fmaf(a0[rr], cA.x, fmaf(a1[rr], cA.y, fmaf(a2[rr], cB.x, base)));
      float val = fminf(t - X[rr], p2[k]);  // = p2 - K2*max(C,0)
      vals[rr][k] = val;
      m[rr] = fmaxf(m[rr], val);
    }
  }
  float err = 0.f;
#pragma unroll
  for (int rr = 0; rr < RPW; ++rr) {
    float mr = wmax(m[rr]);
    float s = 0.f;
#pragma unroll
    for (int k = 0; k < KPL; ++k)
      s += __builtin_amdgcn_exp2f(vals[rr][k] - mr);
    s = wsum(s);
    float pn = fmaf(NEPSLN2, mr + __builtin_amdgcn_logf(s), EPSLOGMU);
    pnew[rr] = pn;
    if (lane == 0) {
      s64(&pout[i0 + rr], pk64(tag_out, pn));   // tagged store: value IS flag
      if (TRACK) err += fabsf(pn - prev[rr]);
    }
  }
  return err;
}

__global__ void __launch_bounds__(NTHREADS, 2) sinkhorn_kernel(
    const float* __restrict__ xg, const float* __restrict__ yg,
    float* __restrict__ out, float* __restrict__ wsf) {
  __shared__ float2 s_xxy[N], s_xzw[N];   // (x,y) and (z, -K2*|p|^2)
  __shared__ float2 s_yxy[N], s_yzw[N];
  __shared__ float s_p2[2][N];            // broadcast buffers (call-parity)
  __shared__ float sh_red[NWAVES];

  u64_t* ws = (u64_t*)wsf;
  const int bid = blockIdx.x;
  const int tid = threadIdx.x;
  const int b = bid & 7;
  const int seg = bid >> 3;
  const int wave = tid >> 6;
  const int lane = tid & 63;
  const int i0 = seg * SEG + wave * RPW;   // first of this wave's rows

  u64_t* u0 = ws + Q_U + (size_t)b * N;            // parity 0
  u64_t* u1 = ws + Q_U + (size_t)(B + b) * N;      // parity 1
  u64_t* v0 = ws + Q_V + (size_t)b * N;
  u64_t* v1 = ws + Q_V + (size_t)(B + b) * N;
  u64_t* errA = ws + Q_ERRA + (size_t)b * 512;     // [2][256] ring-2
  u64_t* errB = ws + Q_ERRB;                       // [4][B] ring-4
  u64_t* emdF = ws + Q_EMD;                        // [NBLOCKS]

  // Stage points into LDS: fully-coalesced (3 float2 per thread = 2 points).
  {
    const float2* xp = (const float2*)(xg + (size_t)b * N * 3) + 3 * tid;
    float2 g0 = xp[0], g1 = xp[1], g2 = xp[2];
    s_xxy[2 * tid]     = g0;
    s_xzw[2 * tid]     = make_float2(g1.x, -K2 * (g0.x * g0.x + g0.y * g0.y + g1.x * g1.x));
    s_xxy[2 * tid + 1] = make_float2(g1.y, g2.x);
    s_xzw[2 * tid + 1] = make_float2(g2.y, -K2 * (g1.y * g1.y + g2.x * g2.x + g2.y * g2.y));
    const float2* yp = (const float2*)(yg + (size_t)b * N * 3) + 3 * tid;
    float2 h0 = yp[0], h1 = yp[1], h2 = yp[2];
    s_yxy[2 * tid]     = h0;
    s_yzw[2 * tid]     = make_float2(h1.x, -K2 * (h0.x * h0.x + h0.y * h0.y + h1.x * h1.x));
    s_yxy[2 * tid + 1] = make_float2(h1.y, h2.x);
    s_yzw[2 * tid + 1] = make_float2(h2.y, -K2 * (h1.y * h1.y + h2.x * h2.x + h2.y * h2.y));
  }
  __syncthreads();

  // ---- u-half(0): u_1 from v_0 = 0; store tagged (tag 1, parity 1) ----
  float un[RPW], un_prev[RPW];
#pragma unroll
  for (int rr = 0; rr < RPW; ++rr) un_prev[rr] = 0.f;
  float my_err = half_compute<true, true>(s_yxy, s_yzw, s_xxy, s_xzw,
                                          nullptr, u1, 0u, 1u, nullptr,
                                          un_prev, un, i0, wave, lane);
  {
    float we = wsum(my_err);
    if (lane == 0) s64(&errA[0 * 256 + seg * 8 + wave], pk64(1u, we));
  }

  int it = 0;
  int cb = 0;                              // s_p2 call-parity
  int final_it;
  bool use_prev;
  for (;;) {
    const uint_t want = (uint_t)(it + 1);
    u64_t* ucur = ((it + 1) & 1) ? u1 : u0;   // holds u_{it+1}
    u64_t* vcur = ((it + 1) & 1) ? v1 : v0;   // will hold v_{it+1}

    // ---- v-half(it): wave0 polls u_{it+1} (the poll IS the sync) ----
    float vn[RPW], vdummy[RPW];
    half_compute<false, false>(s_xxy, s_xzw, s_yxy, s_yzw,
                               ucur, vcur, want, want, s_p2[cb],
                               vdummy, vn, i0, wave, lane);
    cb ^= 1;

    // ---- seg0-wave0 aggregates batch err(it): partials are one compute
    // phase old -> poll hits immediately. Publishes tagged errB. ----
    if (seg == 0 && wave == 0) {
      const u64_t* ea = errA + (it & 1) * 256;
      u64_t pa[4];
#pragma unroll
      for (int q = 0; q < 4; ++q) pa[q] = l64(&ea[lane + (q << 6)]);
      for (;;) {
        bool ok = true;
#pragma unroll
        for (int q = 0; q < 4; ++q) ok &= (tg(pa[q]) == want);
        if (__all(ok)) break;
        __builtin_amdgcn_s_sleep(1);
#pragma unroll
        for (int q = 0; q < 4; ++q)
          if (tg(pa[q]) != want) pa[q] = l64(&ea[lane + (q << 6)]);
      }
      float e = 0.f;
#pragma unroll
      for (int q = 0; q < 4; ++q) e += pay(pa[q]);
      e = wsum(e);
      if (lane == 0) s64(&errB[(it & 3) * 8 + b], pk64(want, e));
    }

    if (it == MAX_ITER - 1) { final_it = MAX_ITER; use_prev = false; break; }

    // Prefetch decision(it) inputs (checked after the next u-half).
    u64_t dp = (lane < B) ? l64(&errB[(it & 3) * 8 + lane]) : 0;

    // ---- u-half(it+1): poll v_{it+1}, store u_{it+2} (tag it+2) ----
#pragma unroll
    for (int rr = 0; rr < RPW; ++rr) un_prev[rr] = un[rr];
    u64_t* unxt = ((it + 2) & 1) ? u1 : u0;
    my_err = half_compute<true, false>(s_yxy, s_yzw, s_xxy, s_xzw,
                                       vcur, unxt, want, (uint_t)(it + 2),
                                       s_p2[cb], un_prev, un, i0, wave, lane);
    cb ^= 1;
    {
      float we = wsum(my_err);
      if (lane == 0)
        s64(&errA[((it + 1) & 1) * 256 + seg * 8 + wave], pk64((uint_t)(it + 2), we));
    }

    // ---- lagged decision(it): prefetched, per-wave, uniform verdict ----
    for (;;) {
      bool ok = (lane >= B) || (tg(dp) == want);
      if (__all(ok)) break;
      __builtin_amdgcn_s_sleep(1);
      if (lane < B && tg(dp) != want) dp = l64(&errB[(it & 3) * 8 + lane]);
    }
    float tot = wsum((lane < B) ? pay(dp) : 0.f);
    if (tot * (1.f / (B * N)) < THRESH) {
      final_it = it + 1; use_prev = true;   // keep u_{it+1} (=un_prev), v_{it+1}
      break;
    }
    ++it;
  }

  // ---- epilogue: emd_b = sum_ij exp((u_i+v_j-C)/EPS)*C  (in K2 scale).
  // Same single-poller + LDS broadcast for v_final. ----
  u64_t* vfin = (final_it & 1) ? v1 : v0;
  float p2e[KPL];
  {
    float* sp = s_p2[cb];
    if (wave == 0) {
      poll16(vfin, (uint_t)final_it, lane, p2e);  // mostly pre-satisfied
#pragma unroll
      for (int k = 0; k < KPL; ++k) sp[lane + (k << 6)] = p2e[k];
    }
    __syncthreads();
    if (wave != 0) {
#pragma unroll
      for (int k = 0; k < KPL; ++k) p2e[k] = sp[lane + (k << 6)];
    }
  }
  float acc = 0.f;
#pragma unroll
  for (int rr = 0; rr < RPW; ++rr) {
    const int i = i0 + rr;
    float2 rA = s_xxy[i], rB = s_xzw[i];
    float a0 = A2K * rA.x, a1 = A2K * rA.y, a2 = A2K * rB.x;
    float X = -rB.y;
    float u2 = (use_prev ? un_prev[rr] : un[rr]) * K2;
#pragma unroll
    for (int k = 0; k < KPL; ++k) {
      const int j = lane + (k << 6);
      float2 cA = s_yxy[j], cB = s_yzw[j];
      float t = fmaf(a0, cA.x, fmaf(a1, cA.y, fmaf(a2, cB.x, cB.y)));
      float kc = fmaxf(X - t, 0.f);   // K2*C
      acc = fmaf(__builtin_amdgcn_exp2f(u2 + p2e[k] - kc), kc, acc);
    }
  }
  float blk = block_sum(acc, sh_red);
  const uint_t ef = (uint_t)(final_it + 1);   // grid-uniform
  if (tid == 0) s64(&emdF[bid], pk64(ef, blk));

  // Block 0 polls all 256 tagged partials directly (one hop).
  if (bid == 0) {
    float part = 0.f;
    if (wave < 4) {
      u64_t pk = l64(&emdF[(wave << 6) + lane]);
      for (;;) {
        if (__all(tg(pk) == ef)) break;
        __builtin_amdgcn_s_sleep(1);
        if (tg(pk) != ef) pk = l64(&emdF[(wave << 6) + lane]);
      }
      part = pay(pk);
    }
    float tot = block_sum(part, sh_red);
    if (tid == 0) out[0] = tot * (1.f / (B * K2));
  }
}

extern "C" void kernel_launch(void* const* d_in, const int* in_sizes, int n_in,
                              void* d_out, int out_size, void* d_ws, size_t ws_size,
                              hipStream_t stream) {
  const float* x = (const float*)d_in[0];
  const float* y = (const float*)d_in[1];
  float* out = (float*)d_out;
  float* ws = (float*)d_ws;
  void* args[] = { (void*)&x, (void*)&y, (void*)&out, (void*)&ws };
  // Cooperative launch only for the co-residency guarantee. All sync is
  // tagged-value polling (exact epoch match) over coherent atomics — one
  // polling wave per block, LDS broadcast to the rest.
  hipLaunchCooperativeKernel((const void*)sinkhorn_kernel,
                             dim3(NBLOCKS), dim3(NTHREADS), args, 0, stream);
}

// Round 13
// 106.138 us; speedup vs baseline: 1.0708x; 1.0331x over previous
//
#include <hip/hip_runtime.h>

typedef unsigned int uint_t;
typedef unsigned long long u64_t;

constexpr int B = 8;
constexpr int N = 1024;
constexpr int NBLOCKS = 256;
constexpr int NTHREADS = 512;
constexpr int NWAVES = NTHREADS / 64;      // 8
constexpr int BPB = NBLOCKS / B;           // 32 blocks per batch
constexpr int SEG = N / BPB;               // 32 rows per block
constexpr int RPW = SEG / NWAVES;          // 4 rows per wave
constexpr int KPL = N / 64;                // 16 columns per lane
constexpr int MAX_ITER = 100;
constexpr float THRESH = 0.1f;
constexpr float K2 = 14.42695040888963f;         // log2(e)/EPS
constexpr float A2K = 2.0f * K2;
constexpr float NEPSLN2 = -0.06931471805599453f; // -EPS*ln2
constexpr float EPSLOGMU = -0.693146156565634f;  // EPS*log(1/N+1e-8)

// R13 = exact revert to R11 (last known good). R12's XCD-census + sc0
// L2-local exchange failed opaquely (hang or regalloc); per the declared
// falsification branch, intra-batch exchange stays agent-scope.
//
// ws offsets in u64 units. u/v are TAGGED cells (epoch<<32)|float_bits,
// double-buffered by parity. Exact-tag polling -> no zero-init anywhere
// (0xAA poison never equals a tag <= 102).
constexpr int Q_U    = 0;                       // [2][B][N]
constexpr int Q_V    = Q_U + 2 * B * N;         // [2][B][N]
constexpr int Q_ERRA = Q_V + 2 * B * N;         // [B][2][256] ring-2 per-wave errs
constexpr int Q_ERRB = Q_ERRA + B * 2 * 256;    // [4][B] ring-4 batch errs
constexpr int Q_EMD  = Q_ERRB + 4 * B;          // [NBLOCKS] tagged emd partials

__device__ __forceinline__ u64_t l64(const u64_t* p) {
  return __hip_atomic_load(p, __ATOMIC_RELAXED, __HIP_MEMORY_SCOPE_AGENT);
}
__device__ __forceinline__ void s64(u64_t* p, u64_t v) {
  __hip_atomic_store(p, v, __ATOMIC_RELAXED, __HIP_MEMORY_SCOPE_AGENT);
}
__device__ __forceinline__ u64_t pk64(uint_t tag, float v) {
  return ((u64_t)tag << 32) | (u64_t)__float_as_uint(v);
}
__device__ __forceinline__ uint_t tg(u64_t v) { return (uint_t)(v >> 32); }
__device__ __forceinline__ float pay(u64_t v) { return __uint_as_float((uint_t)v); }

__device__ __forceinline__ float wsum(float v) {
#pragma unroll
  for (int o = 32; o; o >>= 1) v += __shfl_xor(v, o);
  return v;
}
__device__ __forceinline__ float wmax(float v) {
#pragma unroll
  for (int o = 32; o; o >>= 1) v = fmaxf(v, __shfl_xor(v, o));
  return v;
}

// Deterministic block-wide sum (epilogue only).
__device__ __forceinline__ float block_sum(float v, float* sh) {
  v = wsum(v);
  const int wave = threadIdx.x >> 6;
  const int lane = threadIdx.x & 63;
  if (lane == 0) sh[wave] = v;
  __syncthreads();
  float tot = 0.f;
#pragma unroll
  for (int w = 0; w < NWAVES; ++w) tot += sh[w];
  __syncthreads();
  return tot;
}

// Poll this lane's 16 tagged cells until all match `want` exactly.
__device__ __forceinline__ void poll16(const u64_t* base, uint_t want, int lane,
                                       float (&out)[KPL]) {
  u64_t pk[KPL];
#pragma unroll
  for (int k = 0; k < KPL; ++k) pk[k] = l64(&base[lane + (k << 6)]);
  for (;;) {
    bool ok = true;
#pragma unroll
    for (int k = 0; k < KPL; ++k) ok &= (tg(pk[k]) == want);
    if (__all(ok)) break;
    __builtin_amdgcn_s_sleep(1);
#pragma unroll
    for (int k = 0; k < KPL; ++k)
      if (tg(pk[k]) != want) pk[k] = l64(&base[lane + (k << 6)]);
  }
#pragma unroll
  for (int k = 0; k < KPL; ++k) out[k] = pay(pk[k]) * K2;
}

// One Sinkhorn half-update in base-2 scale (K2 folded in). Only WAVE 0 polls
// the tagged input cells (8 KB/round per BLOCK — R10 had all 8 waves
// redundantly polling identical data); payloads broadcast via an LDS buffer
// (stride-1, conflict-free), double-buffered by call parity.
template <bool TRACK, bool PIN_ZERO>
__device__ __forceinline__ float half_compute(
    const float2* __restrict__ cxy, const float2* __restrict__ czw,
    const float2* __restrict__ rxy, const float2* __restrict__ rzw,
    const u64_t* __restrict__ pin, u64_t* __restrict__ pout,
    uint_t tag_in, uint_t tag_out, float* __restrict__ s_p2,
    const float (&prev)[RPW], float (&pnew)[RPW], int i0, int wave, int lane) {
  float p2[KPL];
  if (PIN_ZERO) {
#pragma unroll
    for (int k = 0; k < KPL; ++k) p2[k] = 0.f;
  } else {
    if (wave == 0) {
      poll16(pin, tag_in, lane, p2);
#pragma unroll
      for (int k = 0; k < KPL; ++k) s_p2[lane + (k << 6)] = p2[k];
    }
    __syncthreads();
    if (wave != 0) {
#pragma unroll
      for (int k = 0; k < KPL; ++k) p2[k] = s_p2[lane + (k << 6)];
    }
  }

  float a0[RPW], a1[RPW], a2[RPW], X[RPW], m[RPW];
  float vals[RPW][KPL];
#pragma unroll
  for (int rr = 0; rr < RPW; ++rr) {
    float2 rA = rxy[i0 + rr], rB = rzw[i0 + rr];   // broadcast
    a0[rr] = A2K * rA.x; a1[rr] = A2K * rA.y; a2[rr] = A2K * rB.x;
    X[rr] = -rB.y;                       // rB.y = -K2*|r|^2
    m[rr] = -3.4e38f;
  }
#pragma unroll
  for (int k = 0; k < KPL; ++k) {
    const int j = lane + (k << 6);
    float2 cA = cxy[j], cB = czw[j];
    float base = cB.y + p2[k];           // fold pin into the fma chain
#pragma unroll
    for (int rr = 0; rr < RPW; ++rr) {
      float t = fmaf(a0[rr], cA.x, fmaf(a1[rr], cA.y, fmaf(a2[rr], cB.x, base)));
      float val = fminf(t - X[rr], p2[k]);  // = p2 - K2*max(C,0)
      vals[rr][k] = val;
      m[rr] = fmaxf(m[rr], val);
    }
  }
  float err = 0.f;
#pragma unroll
  for (int rr = 0; rr < RPW; ++rr) {
    float mr = wmax(m[rr]);
    float s = 0.f;
#pragma unroll
    for (int k = 0; k < KPL; ++k)
      s += __builtin_amdgcn_exp2f(vals[rr][k] - mr);
    s = wsum(s);
    float pn = fmaf(NEPSLN2, mr + __builtin_amdgcn_logf(s), EPSLOGMU);
    pnew[rr] = pn;
    if (lane == 0) {
      s64(&pout[i0 + rr], pk64(tag_out, pn));   // tagged store: value IS flag
      if (TRACK) err += fabsf(pn - prev[rr]);
    }
  }
  return err;
}

__global__ void __launch_bounds__(NTHREADS, 2) sinkhorn_kernel(
    const float* __restrict__ xg, const float* __restrict__ yg,
    float* __restrict__ out, float* __restrict__ wsf) {
  __shared__ float2 s_xxy[N], s_xzw[N];   // (x,y) and (z, -K2*|p|^2)
  __shared__ float2 s_yxy[N], s_yzw[N];
  __shared__ float s_p2[2][N];            // broadcast buffers (call-parity)
  __shared__ float sh_red[NWAVES];

  u64_t* ws = (u64_t*)wsf;
  const int bid = blockIdx.x;
  const int tid = threadIdx.x;
  const int b = bid & 7;
  const int seg = bid >> 3;
  const int wave = tid >> 6;
  const int lane = tid & 63;
  const int i0 = seg * SEG + wave * RPW;   // first of this wave's rows

  u64_t* u0 = ws + Q_U + (size_t)b * N;            // parity 0
  u64_t* u1 = ws + Q_U + (size_t)(B + b) * N;      // parity 1
  u64_t* v0 = ws + Q_V + (size_t)b * N;
  u64_t* v1 = ws + Q_V + (size_t)(B + b) * N;
  u64_t* errA = ws + Q_ERRA + (size_t)b * 512;     // [2][256] ring-2
  u64_t* errB = ws + Q_ERRB;                       // [4][B] ring-4
  u64_t* emdF = ws + Q_EMD;                        // [NBLOCKS]

  // Stage points into LDS: fully-coalesced (3 float2 per thread = 2 points).
  {
    const float2* xp = (const float2*)(xg + (size_t)b * N * 3) + 3 * tid;
    float2 g0 = xp[0], g1 = xp[1], g2 = xp[2];
    s_xxy[2 * tid]     = g0;
    s_xzw[2 * tid]     = make_float2(g1.x, -K2 * (g0.x * g0.x + g0.y * g0.y + g1.x * g1.x));
    s_xxy[2 * tid + 1] = make_float2(g1.y, g2.x);
    s_xzw[2 * tid + 1] = make_float2(g2.y, -K2 * (g1.y * g1.y + g2.x * g2.x + g2.y * g2.y));
    const float2* yp = (const float2*)(yg + (size_t)b * N * 3) + 3 * tid;
    float2 h0 = yp[0], h1 = yp[1], h2 = yp[2];
    s_yxy[2 * tid]     = h0;
    s_yzw[2 * tid]     = make_float2(h1.x, -K2 * (h0.x * h0.x + h0.y * h0.y + h1.x * h1.x));
    s_yxy[2 * tid + 1] = make_float2(h1.y, h2.x);
    s_yzw[2 * tid + 1] = make_float2(h2.y, -K2 * (h1.y * h1.y + h2.x * h2.x + h2.y * h2.y));
  }
  __syncthreads();

  // ---- u-half(0): u_1 from v_0 = 0; store tagged (tag 1, parity 1) ----
  float un[RPW], un_prev[RPW];
#pragma unroll
  for (int rr = 0; rr < RPW; ++rr) un_prev[rr] = 0.f;
  float my_err = half_compute<true, true>(s_yxy, s_yzw, s_xxy, s_xzw,
                                          nullptr, u1, 0u, 1u, nullptr,
                                          un_prev, un, i0, wave, lane);
  {
    float we = wsum(my_err);
    if (lane == 0) s64(&errA[0 * 256 + seg * 8 + wave], pk64(1u, we));
  }

  int it = 0;
  int cb = 0;                              // s_p2 call-parity
  int final_it;
  bool use_prev;
  for (;;) {
    const uint_t want = (uint_t)(it + 1);
    u64_t* ucur = ((it + 1) & 1) ? u1 : u0;   // holds u_{it+1}
    u64_t* vcur = ((it + 1) & 1) ? v1 : v0;   // will hold v_{it+1}

    // ---- v-half(it): wave0 polls u_{it+1} (the poll IS the sync) ----
    float vn[RPW], vdummy[RPW];
    half_compute<false, false>(s_xxy, s_xzw, s_yxy, s_yzw,
                               ucur, vcur, want, want, s_p2[cb],
                               vdummy, vn, i0, wave, lane);
    cb ^= 1;

    // ---- seg0-wave0 aggregates batch err(it): partials are one compute
    // phase old -> poll hits immediately. Publishes tagged errB. ----
    if (seg == 0 && wave == 0) {
      const u64_t* ea = errA + (it & 1) * 256;
      u64_t pa[4];
#pragma unroll
      for (int q = 0; q < 4; ++q) pa[q] = l64(&ea[lane + (q << 6)]);
      for (;;) {
        bool ok = true;
#pragma unroll
        for (int q = 0; q < 4; ++q) ok &= (tg(pa[q]) == want);
        if (__all(ok)) break;
        __builtin_amdgcn_s_sleep(1);
#pragma unroll
        for (int q = 0; q < 4; ++q)
          if (tg(pa[q]) != want) pa[q] = l64(&ea[lane + (q << 6)]);
      }
      float e = 0.f;
#pragma unroll
      for (int q = 0; q < 4; ++q) e += pay(pa[q]);
      e = wsum(e);
      if (lane == 0) s64(&errB[(it & 3) * 8 + b], pk64(want, e));
    }

    if (it == MAX_ITER - 1) { final_it = MAX_ITER; use_prev = false; break; }

    // Prefetch decision(it) inputs (checked after the next u-half).
    u64_t dp = (lane < B) ? l64(&errB[(it & 3) * 8 + lane]) : 0;

    // ---- u-half(it+1): poll v_{it+1}, store u_{it+2} (tag it+2) ----
#pragma unroll
    for (int rr = 0; rr < RPW; ++rr) un_prev[rr] = un[rr];
    u64_t* unxt = ((it + 2) & 1) ? u1 : u0;
    my_err = half_compute<true, false>(s_yxy, s_yzw, s_xxy, s_xzw,
                                       vcur, unxt, want, (uint_t)(it + 2),
                                       s_p2[cb], un_prev, un, i0, wave, lane);
    cb ^= 1;
    {
      float we = wsum(my_err);
      if (lane == 0)
        s64(&errA[((it + 1) & 1) * 256 + seg * 8 + wave], pk64((uint_t)(it + 2), we));
    }

    // ---- lagged decision(it): prefetched, per-wave, uniform verdict ----
    for (;;) {
      bool ok = (lane >= B) || (tg(dp) == want);
      if (__all(ok)) break;
      __builtin_amdgcn_s_sleep(1);
      if (lane < B && tg(dp) != want) dp = l64(&errB[(it & 3) * 8 + lane]);
    }
    float tot = wsum((lane < B) ? pay(dp) : 0.f);
    if (tot * (1.f / (B * N)) < THRESH) {
      final_it = it + 1; use_prev = true;   // keep u_{it+1} (=un_prev), v_{it+1}
      break;
    }
    ++it;
  }

  // ---- epilogue: emd_b = sum_ij exp((u_i+v_j-C)/EPS)*C  (in K2 scale).
  // Same single-poller + LDS broadcast for v_final. ----
  u64_t* vfin = (final_it & 1) ? v1 : v0;
  float p2e[KPL];
  {
    float* sp = s_p2[cb];
    if (wave == 0) {
      poll16(vfin, (uint_t)final_it, lane, p2e);  // mostly pre-satisfied
#pragma unroll
      for (int k = 0; k < KPL; ++k) sp[lane + (k << 6)] = p2e[k];
    }
    __syncthreads();
    if (wave != 0) {
#pragma unroll
      for (int k = 0; k < KPL; ++k) p2e[k] = sp[lane + (k << 6)];
    }
  }
  float acc = 0.f;
#pragma unroll
  for (int rr = 0; rr < RPW; ++rr) {
    const int i = i0 + rr;
    float2 rA = s_xxy[i], rB = s_xzw[i];
    float a0 = A2K * rA.x, a1 = A2K * rA.y, a2 = A2K * rB.x;
    float X = -rB.y;
    float u2 = (use_prev ? un_prev[rr] : un[rr]) * K2;
#pragma unroll
    for (int k = 0; k < KPL; ++k) {
      const int j = lane + (k << 6);
      float2 cA = s_yxy[j], cB = s_yzw[j];
      float t = fmaf(a0, cA.x, fmaf(a1, cA.y, fmaf(a2, cB.x, cB.y)));
      float kc = fmaxf(X - t, 0.f);   // K2*C
      acc = fmaf(__builtin_amdgcn_exp2f(u2 + p2e[k] - kc), kc, acc);
    }
  }
  float blk = block_sum(acc, sh_red);
  const uint_t ef = (uint_t)(final_it + 1);   // grid-uniform
  if (tid == 0) s64(&emdF[bid], pk64(ef, blk));

  // Block 0 polls all 256 tagged partials directly (one hop).
  if (bid == 0) {
    float part = 0.f;
    if (wave < 4) {
      u64_t pk = l64(&emdF[(wave << 6) + lane]);
      for (;;) {
        if (__all(tg(pk) == ef)) break;
        __builtin_amdgcn_s_sleep(1);
        if (tg(pk) != ef) pk = l64(&emdF[(wave << 6) + lane]);
      }
      part = pay(pk);
    }
    float tot = block_sum(part, sh_red);
    if (tid == 0) out[0] = tot * (1.f / (B * K2));
  }
}

extern "C" void kernel_launch(void* const* d_in, const int* in_sizes, int n_in,
                              void* d_out, int out_size, void* d_ws, size_t ws_size,
                              hipStream_t stream) {
  const float* x = (const float*)d_in[0];
  const float* y = (const float*)d_in[1];
  float* out = (float*)d_out;
  float* ws = (float*)d_ws;
  void* args[] = { (void*)&x, (void*)&y, (void*)&out, (void*)&ws };
  // Cooperative launch only for the co-residency guarantee. All sync is
  // tagged-value polling (exact epoch match) over coherent atomics — one
  // polling wave per block, LDS broadcast to the rest.
  hipLaunchCooperativeKernel((const void*)sinkhorn_kernel,
                             dim3(NBLOCKS), dim3(NTHREADS), args, 0, stream);
}